// Round 2
// baseline (1812.300 us; speedup 1.0000x reference)
//
#include <hip/hip_runtime.h>
#include <hip/hip_bf16.h>
#include <hip/hip_cooperative_groups.h>
namespace cg = cooperative_groups;

typedef __bf16 bf16x8 __attribute__((ext_vector_type(8)));
typedef float f32x4 __attribute__((ext_vector_type(4)));

#define UNITS   2048
#define NC      6144
#define TSTEPS  32

__device__ __forceinline__ float sigmoid_f(float v){ return 1.0f/(1.0f+__expf(-v)); }

// ---- prep: cast x to bf16; init h buffers (hf [s][u], hhi8/hlo8 [u>>3][s][u&7]) ----
__global__ __launch_bounds__(256) void prep_misc(
    const float* __restrict__ x, const float* __restrict__ h0,
    __bf16* __restrict__ xb, float* __restrict__ hf,
    __bf16* __restrict__ hhi8, __bf16* __restrict__ hlo8)
{
  int i = blockIdx.x*256 + threadIdx.x;
  if (i < 524288) xb[i] = (__bf16)x[i];
  if (i < 131072) {
    int s = i >> 11, u = i & 2047;
    float v = h0[((s & 7) << 11) + u];
    hf[i] = v;
    __bf16 hi = (__bf16)v;
    int ia = (((u >> 3) << 6) + s) * 8 + (u & 7);
    hhi8[ia] = hi;
    hlo8[ia] = (__bf16)(v - (float)hi);
  }
}

// ---- transpose+cast: src (2048 x 6144 f32, KxN) -> dst (6144 x 2048 bf16, NxK) ----
__global__ __launch_bounds__(256) void transpose_cast(
    const float* __restrict__ W, const float* __restrict__ U,
    __bf16* __restrict__ Wt, __bf16* __restrict__ Ut)
{
  __shared__ float tile[64][65];
  const float* src = blockIdx.z ? U : W;
  __bf16* dst = blockIdx.z ? Ut : Wt;
  int n0 = blockIdx.x*64, k0 = blockIdx.y*64;
  int lane = threadIdx.x & 63, grp = threadIdx.x >> 6;
  #pragma unroll
  for (int r = grp; r < 64; r += 4)
    tile[r][lane] = src[(size_t)(k0+r)*NC + n0 + lane];
  __syncthreads();
  #pragma unroll
  for (int r = grp; r < 64; r += 4)
    dst[(size_t)(n0+r)*UNITS + k0 + lane] = (__bf16)tile[lane][r];
}

// ---- xp GEMM, LDS-staged B, register prefix over l ----
// grid (96 n-tiles of 64, 4 bt-tiles of 64), 512 threads (8 waves = 4 M x 2 N-halves)
__global__ __launch_bounds__(512) void xp_gemm(
    const __bf16* __restrict__ xb, const __bf16* __restrict__ Wt,
    const float* __restrict__ bin, float* __restrict__ xp)
{
  __shared__ __align__(16) short sB[64*256];   // 32 KB, [col][k256] swizzled
  int n0 = blockIdx.x*64, bt0 = blockIdx.y*64;
  int tid = threadIdx.x;
  int lane = tid & 63, w = tid >> 6;
  int wm = w & 3, wn = w >> 2;
  int nl = lane & 15, kg = lane >> 4;
  f32x4 acc[2] = {{0,0,0,0},{0,0,0,0}};
  for (int l = 0; l < 8; ++l) {
    __syncthreads();
    #pragma unroll
    for (int i = 0; i < 4; ++i) {
      int e = tid + i*512;                  // 2048 chunks: col=e>>5, ch=e&31
      int col = e >> 5, ch = e & 31;
      bf16x8 v = *(const bf16x8*)(Wt + (size_t)(n0+col)*UNITS + l*256 + ch*8);
      int off = ((col<<9) | (ch<<4)) ^ ((col&7)<<4);
      *(bf16x8*)((char*)sB + off) = v;
    }
    __syncthreads();
    const __bf16* abase = xb + ((size_t)(bt0 + wm*16 + nl)*8 + l)*256 + kg*8;
    #pragma unroll
    for (int kk = 0; kk < 256; kk += 32) {
      bf16x8 a = *(const bf16x8*)(abase + kk);
      #pragma unroll
      for (int nt = 0; nt < 2; ++nt) {
        int col = wn*32 + nt*16 + nl;
        int off = ((col<<9) | ((kk + kg*8)<<1)) ^ ((col&7)<<4);
        bf16x8 bfr = *(const bf16x8*)((const char*)sB + off);
        acc[nt] = __builtin_amdgcn_mfma_f32_16x16x32_bf16(a, bfr, acc[nt], 0,0,0);
      }
    }
    int orow = bt0 + wm*16 + kg*4;
    #pragma unroll
    for (int nt = 0; nt < 2; ++nt) {
      int col = n0 + wn*32 + nt*16 + nl;
      float bv = bin[col];
      #pragma unroll
      for (int r = 0; r < 4; ++r) {
        int rr = orow + r;
        int b_ = rr >> 5, t_ = rr & 31;
        xp[(size_t)((l*8 + b_)*32 + t_)*NC + col] = acc[nt][r] + bv;
      }
    }
  }
}

// ---- persistent GRU: all 32 steps, U resident in LDS(z,r)+VGPR(hh) ----
// grid 256 blocks (128 unit-groups x 2 seq-halves), 512 threads (8 waves = 2M x 4Kq)
__global__ __launch_bounds__(512, 2) void gru_persist(
    const __bf16* __restrict__ Ut, const float* __restrict__ xp, const float* __restrict__ brec,
    float* __restrict__ hf0, float* __restrict__ hf1,
    __bf16* __restrict__ hhi0, __bf16* __restrict__ hhi1,
    __bf16* __restrict__ hlo0, __bf16* __restrict__ hlo1,
    float* __restrict__ ret, float* __restrict__ st)
{
  __shared__ __align__(16) short sU[2*16*2048];    // 128 KB: gates z,r [g][col16][k2048] swizzled
  __shared__ __align__(16) f32x4 sRed[6][3][64];   // 18 KB reduction scratch

  int tid = threadIdx.x;
  int lane = tid & 63, w = tid >> 6;
  int m = w & 1, kq = w >> 1;
  int u0 = (blockIdx.x >> 1) * 16;
  int s0 = (blockIdx.x & 1) * 32;
  int nl = lane & 15, kg = lane >> 4;

  // stage U gates z,r into LDS (coalesced along k)
  #pragma unroll
  for (int i = 0; i < 16; ++i) {
    int e = tid + i*512;                 // 8192 chunks: g=e>>12, col=(e>>8)&15, ch=e&255
    int g = e >> 12, col = (e >> 8) & 15, ch = e & 255;
    bf16x8 v = *(const bf16x8*)(Ut + (size_t)(g*UNITS + u0 + col)*UNITS + ch*8);
    int off = ((g<<16) | (col<<12) | (ch<<4)) ^ ((col&7)<<4);
    *(bf16x8*)((char*)sU + off) = v;
  }
  // gate hh fragments in VGPRs: wave (m,kq) holds K-slice kq*512..+512
  bf16x8 uh[16];
  #pragma unroll
  for (int kk = 0; kk < 16; ++kk)
    uh[kk] = *(const bf16x8*)(Ut + (size_t)(2*UNITS + u0 + nl)*UNITS + kq*512 + kk*32 + kg*8);
  __syncthreads();

  cg::grid_group grid = cg::this_grid();

  for (int t = 0; t < TSTEPS; ++t) {
    const float*  hfc  = (t&1) ? hf1  : hf0;
    float*        hfn  = (t&1) ? hf0  : hf1;
    const __bf16* hhic = (t&1) ? hhi1 : hhi0;
    __bf16*       hhin = (t&1) ? hhi0 : hhi1;
    const __bf16* hloc = (t&1) ? hlo1 : hlo0;
    __bf16*       hlon = (t&1) ? hlo0 : hlo1;

    f32x4 az = {0,0,0,0}, ar = {0,0,0,0}, ah = {0,0,0,0};
    const __bf16* Ah = hhic + ((size_t)((kq*64 + kg)*64) + s0 + m*16 + nl)*8;
    const __bf16* Al = hloc + ((size_t)((kq*64 + kg)*64) + s0 + m*16 + nl)*8;
    #pragma unroll
    for (int kk = 0; kk < 16; ++kk) {
      bf16x8 avh = *(const bf16x8*)(Ah + (size_t)kk*2048);
      bf16x8 avl = *(const bf16x8*)(Al + (size_t)kk*2048);
      int kb = (kq*512 + kk*32 + kg*8) << 1;
      int offz = ((0<<16) | (nl<<12) | kb) ^ ((nl&7)<<4);
      int offr = ((1<<16) | (nl<<12) | kb) ^ ((nl&7)<<4);
      bf16x8 bz = *(const bf16x8*)((const char*)sU + offz);
      bf16x8 br = *(const bf16x8*)((const char*)sU + offr);
      az = __builtin_amdgcn_mfma_f32_16x16x32_bf16(avl, bz, az, 0,0,0);
      az = __builtin_amdgcn_mfma_f32_16x16x32_bf16(avh, bz, az, 0,0,0);
      ar = __builtin_amdgcn_mfma_f32_16x16x32_bf16(avl, br, ar, 0,0,0);
      ar = __builtin_amdgcn_mfma_f32_16x16x32_bf16(avh, br, ar, 0,0,0);
      ah = __builtin_amdgcn_mfma_f32_16x16x32_bf16(avl, uh[kk], ah, 0,0,0);
      ah = __builtin_amdgcn_mfma_f32_16x16x32_bf16(avh, uh[kk], ah, 0,0,0);
    }
    if (kq) {
      int slot = (kq-1)*2 + m;
      sRed[slot][0][lane] = az; sRed[slot][1][lane] = ar; sRed[slot][2][lane] = ah;
    }
    __syncthreads();
    if (kq == 0) {
      #pragma unroll
      for (int p = 0; p < 3; ++p) {
        int slot = p*2 + m;
        az += sRed[slot][0][lane]; ar += sRed[slot][1][lane]; ah += sRed[slot][2][lane];
      }
      int u = u0 + nl;
      float bz_ = brec[u], br_ = brec[2048+u], bh_ = brec[4096+u];
      int mm = u0 >> 8;
      #pragma unroll
      for (int r = 0; r < 4; ++r) {
        int s = s0 + m*16 + kg*4 + r;
        const float* xrow = xp + ((size_t)s*32 + t)*NC;
        float z  = sigmoid_f(xrow[u]        + az[r] + bz_);
        float rg = sigmoid_f(xrow[2048+u]   + ar[r] + br_);
        float hh = tanhf(xrow[4096+u] + rg*(ah[r] + bh_));
        float hold = hfc[(size_t)s*UNITS + u];
        float hnew = z*hold + (1.0f - z)*hh;
        hfn[(size_t)s*UNITS + u] = hnew;
        __bf16 hi = (__bf16)hnew;
        int ia = (((u >> 3) << 6) + s)*8 + (u & 7);
        hhin[ia] = hi;
        hlon[ia] = (__bf16)(hnew - (float)hi);
        if ((s >> 3) == mm)
          ret[(size_t)((((s & 7)*32 + t) << 3) + mm)*256 + (u & 255)] = hnew;
        if (t == 31 && s >= 56) st[(size_t)(s - 56)*UNITS + u] = hnew;
      }
      __threadfence();
    }
    grid.sync();
  }
}

extern "C" void kernel_launch(void* const* d_in, const int* in_sizes, int n_in,
                              void* d_out, int out_size, void* d_ws, size_t ws_size,
                              hipStream_t stream) {
  const float* x  = (const float*)d_in[0];
  const float* h0 = (const float*)d_in[1];
  const float* W  = (const float*)d_in[2];
  const float* U  = (const float*)d_in[3];
  const float* b  = (const float*)d_in[4];
  float* ret = (float*)d_out;
  float* st  = ret + 524288;

  char* p = (char*)d_ws;
  __bf16* Ut = (__bf16*)p; p += 25165824;
  __bf16* Wt = (__bf16*)p; p += 25165824;
  __bf16* xb = (__bf16*)p; p += 1048576;
  float*  xp = (float*)p;  p += 50331648;
  float*  hf0  = (float*)p;  p += 524288;
  float*  hf1  = (float*)p;  p += 524288;
  __bf16* hhi0 = (__bf16*)p; p += 262144;
  __bf16* hhi1 = (__bf16*)p; p += 262144;
  __bf16* hlo0 = (__bf16*)p; p += 262144;
  __bf16* hlo1 = (__bf16*)p; p += 262144;

  prep_misc<<<2048, 256, 0, stream>>>(x, h0, xb, hf0, hhi0, hlo0);
  transpose_cast<<<dim3(96,32,2), 256, 0, stream>>>(W, U, Wt, Ut);
  xp_gemm<<<dim3(96,4), 512, 0, stream>>>(xb, Wt, b, xp);

  const float* brec = b + NC;
  void* args[] = { (void*)&Ut, (void*)&xp, (void*)&brec,
                   (void*)&hf0, (void*)&hf1, (void*)&hhi0, (void*)&hhi1,
                   (void*)&hlo0, (void*)&hlo1, (void*)&ret, (void*)&st };
  hipLaunchCooperativeKernel((const void*)gru_persist, dim3(256), dim3(512),
                             args, 0, stream);
}

// Round 3
// 813.654 us; speedup vs baseline: 2.2274x; 2.2274x over previous
//
#include <hip/hip_runtime.h>
#include <hip/hip_bf16.h>

typedef __bf16 bf16x8 __attribute__((ext_vector_type(8)));
typedef float f32x4 __attribute__((ext_vector_type(4)));

#define UNITS   2048
#define NC      6144
#define TSTEPS  32

__device__ __forceinline__ float sigmoid_f(float v){ return 1.0f/(1.0f+__expf(-v)); }

// ---- prep: cast x to bf16; init h buffers (hf [s][u], hhi8/hlo8 [u>>3][s][u&7]);
//      idempotently reset barrier counter ----
__global__ __launch_bounds__(256) void prep_misc(
    const float* __restrict__ x, const float* __restrict__ h0,
    __bf16* __restrict__ xb, float* __restrict__ hf,
    __bf16* __restrict__ hhi8, __bf16* __restrict__ hlo8,
    unsigned* __restrict__ bar)
{
  int i = blockIdx.x*256 + threadIdx.x;
  if (i == 0) bar[0] = 0;               // arrival counter; gen (bar[32]) stays monotonic
  if (i < 524288) xb[i] = (__bf16)x[i];
  if (i < 131072) {
    int s = i >> 11, u = i & 2047;
    float v = h0[((s & 7) << 11) + u];
    hf[i] = v;
    __bf16 hi = (__bf16)v;
    int ia = (((u >> 3) << 6) + s) * 8 + (u & 7);
    hhi8[ia] = hi;
    hlo8[ia] = (__bf16)(v - (float)hi);
  }
}

// ---- transpose+cast: src (2048 x 6144 f32, KxN) -> dst (6144 x 2048 bf16, NxK) ----
__global__ __launch_bounds__(256) void transpose_cast(
    const float* __restrict__ W, const float* __restrict__ U,
    __bf16* __restrict__ Wt, __bf16* __restrict__ Ut)
{
  __shared__ float tile[64][65];
  const float* src = blockIdx.z ? U : W;
  __bf16* dst = blockIdx.z ? Ut : Wt;
  int n0 = blockIdx.x*64, k0 = blockIdx.y*64;
  int lane = threadIdx.x & 63, grp = threadIdx.x >> 6;
  #pragma unroll
  for (int r = grp; r < 64; r += 4)
    tile[r][lane] = src[(size_t)(k0+r)*NC + n0 + lane];
  __syncthreads();
  #pragma unroll
  for (int r = grp; r < 64; r += 4)
    dst[(size_t)(n0+r)*UNITS + k0 + lane] = (__bf16)tile[lane][r];
}

// ---- xp GEMM, LDS-staged B, register prefix over l ----
__global__ __launch_bounds__(512) void xp_gemm(
    const __bf16* __restrict__ xb, const __bf16* __restrict__ Wt,
    const float* __restrict__ bin, float* __restrict__ xp)
{
  __shared__ __align__(16) short sB[64*256];   // 32 KB, [col][k256] swizzled
  int n0 = blockIdx.x*64, bt0 = blockIdx.y*64;
  int tid = threadIdx.x;
  int lane = tid & 63, w = tid >> 6;
  int wm = w & 3, wn = w >> 2;
  int nl = lane & 15, kg = lane >> 4;
  f32x4 acc[2] = {{0,0,0,0},{0,0,0,0}};
  for (int l = 0; l < 8; ++l) {
    __syncthreads();
    #pragma unroll
    for (int i = 0; i < 4; ++i) {
      int e = tid + i*512;
      int col = e >> 5, ch = e & 31;
      bf16x8 v = *(const bf16x8*)(Wt + (size_t)(n0+col)*UNITS + l*256 + ch*8);
      int off = ((col<<9) | (ch<<4)) ^ ((col&7)<<4);
      *(bf16x8*)((char*)sB + off) = v;
    }
    __syncthreads();
    const __bf16* abase = xb + ((size_t)(bt0 + wm*16 + nl)*8 + l)*256 + kg*8;
    #pragma unroll
    for (int kk = 0; kk < 256; kk += 32) {
      bf16x8 a = *(const bf16x8*)(abase + kk);
      #pragma unroll
      for (int nt = 0; nt < 2; ++nt) {
        int col = wn*32 + nt*16 + nl;
        int off = ((col<<9) | ((kk + kg*8)<<1)) ^ ((col&7)<<4);
        bf16x8 bfr = *(const bf16x8*)((const char*)sB + off);
        acc[nt] = __builtin_amdgcn_mfma_f32_16x16x32_bf16(a, bfr, acc[nt], 0,0,0);
      }
    }
    int orow = bt0 + wm*16 + kg*4;
    #pragma unroll
    for (int nt = 0; nt < 2; ++nt) {
      int col = n0 + wn*32 + nt*16 + nl;
      float bv = bin[col];
      #pragma unroll
      for (int r = 0; r < 4; ++r) {
        int rr = orow + r;
        int b_ = rr >> 5, t_ = rr & 31;
        xp[(size_t)((l*8 + b_)*32 + t_)*NC + col] = acc[nt][r] + bv;
      }
    }
  }
}

// ---- lightweight device-wide barrier (counter + generation) ----
__device__ __forceinline__ void grid_barrier(unsigned* cnt, unsigned* gen, unsigned nb)
{
  __syncthreads();
  if (threadIdx.x == 0) {
    __threadfence();   // release: drain block's writes to device scope
    unsigned g = __hip_atomic_load(gen, __ATOMIC_RELAXED, __HIP_MEMORY_SCOPE_AGENT);
    unsigned a = __hip_atomic_fetch_add(cnt, 1u, __ATOMIC_ACQ_REL, __HIP_MEMORY_SCOPE_AGENT);
    if (a == nb - 1u) {
      __hip_atomic_store(cnt, 0u, __ATOMIC_RELAXED, __HIP_MEMORY_SCOPE_AGENT);
      __hip_atomic_store(gen, g + 1u, __ATOMIC_RELEASE, __HIP_MEMORY_SCOPE_AGENT);
    } else {
      while (__hip_atomic_load(gen, __ATOMIC_RELAXED, __HIP_MEMORY_SCOPE_AGENT) == g)
        __builtin_amdgcn_s_sleep(2);
    }
    __threadfence();   // acquire: invalidate stale cached lines
  }
  __syncthreads();
}

// ---- persistent GRU: all 32 steps, U resident in LDS(z,r)+VGPR(hh) ----
__global__ __launch_bounds__(512, 2) void gru_persist(
    const __bf16* __restrict__ Ut, const float* __restrict__ xp, const float* __restrict__ brec,
    float* __restrict__ hf0, float* __restrict__ hf1,
    __bf16* __restrict__ hhi0, __bf16* __restrict__ hhi1,
    __bf16* __restrict__ hlo0, __bf16* __restrict__ hlo1,
    float* __restrict__ ret, float* __restrict__ st, unsigned* __restrict__ bar)
{
  __shared__ __align__(16) short sU[2*16*2048];    // 128 KB: gates z,r [g][col16][k2048] swizzled
  __shared__ __align__(16) f32x4 sRed[6][3][64];   // 18 KB reduction scratch

  int tid = threadIdx.x;
  int lane = tid & 63, w = tid >> 6;
  int m = w & 1, kq = w >> 1;
  int u0 = (blockIdx.x >> 1) * 16;
  int s0 = (blockIdx.x & 1) * 32;
  int nl = lane & 15, kg = lane >> 4;
  unsigned nb = gridDim.x;

  // stage U gates z,r into LDS (coalesced along k)
  #pragma unroll
  for (int i = 0; i < 16; ++i) {
    int e = tid + i*512;
    int g = e >> 12, col = (e >> 8) & 15, ch = e & 255;
    bf16x8 v = *(const bf16x8*)(Ut + (size_t)(g*UNITS + u0 + col)*UNITS + ch*8);
    int off = ((g<<16) | (col<<12) | (ch<<4)) ^ ((col&7)<<4);
    *(bf16x8*)((char*)sU + off) = v;
  }
  // gate hh fragments in VGPRs: wave (m,kq) holds K-slice kq*512..+512
  bf16x8 uh[16];
  #pragma unroll
  for (int kk = 0; kk < 16; ++kk)
    uh[kk] = *(const bf16x8*)(Ut + (size_t)(2*UNITS + u0 + nl)*UNITS + kq*512 + kk*32 + kg*8);
  __syncthreads();

  int u = u0 + nl;
  float bz_ = brec[u], br_ = brec[2048+u], bh_ = brec[4096+u];
  int mm = u0 >> 8;

  for (int t = 0; t < TSTEPS; ++t) {
    const float*  hfc  = (t&1) ? hf1  : hf0;
    float*        hfn  = (t&1) ? hf0  : hf1;
    const __bf16* hhic = (t&1) ? hhi1 : hhi0;
    __bf16*       hhin = (t&1) ? hhi0 : hhi1;
    const __bf16* hloc = (t&1) ? hlo1 : hlo0;
    __bf16*       hlon = (t&1) ? hlo0 : hlo1;

    // hoist scattered epilogue loads: hide their L3 latency under the MFMA loop
    float xzv[4], xrv[4], xhv[4], hov[4];
    if (kq == 0) {
      #pragma unroll
      for (int r = 0; r < 4; ++r) {
        int s = s0 + m*16 + kg*4 + r;
        const float* xrow = xp + ((size_t)s*32 + t)*NC;
        xzv[r] = xrow[u];
        xrv[r] = xrow[2048+u];
        xhv[r] = xrow[4096+u];
        hov[r] = hfc[(size_t)s*UNITS + u];
      }
    }

    f32x4 az = {0,0,0,0}, ar = {0,0,0,0}, ah = {0,0,0,0};
    const __bf16* Ah = hhic + ((size_t)((kq*64 + kg)*64) + s0 + m*16 + nl)*8;
    const __bf16* Al = hloc + ((size_t)((kq*64 + kg)*64) + s0 + m*16 + nl)*8;
    #pragma unroll
    for (int kk = 0; kk < 16; ++kk) {
      bf16x8 avh = *(const bf16x8*)(Ah + (size_t)kk*2048);
      bf16x8 avl = *(const bf16x8*)(Al + (size_t)kk*2048);
      int kb = (kq*512 + kk*32 + kg*8) << 1;
      int offz = ((0<<16) | (nl<<12) | kb) ^ ((nl&7)<<4);
      int offr = ((1<<16) | (nl<<12) | kb) ^ ((nl&7)<<4);
      bf16x8 bz = *(const bf16x8*)((const char*)sU + offz);
      bf16x8 br = *(const bf16x8*)((const char*)sU + offr);
      az = __builtin_amdgcn_mfma_f32_16x16x32_bf16(avl, bz, az, 0,0,0);
      az = __builtin_amdgcn_mfma_f32_16x16x32_bf16(avh, bz, az, 0,0,0);
      ar = __builtin_amdgcn_mfma_f32_16x16x32_bf16(avl, br, ar, 0,0,0);
      ar = __builtin_amdgcn_mfma_f32_16x16x32_bf16(avh, br, ar, 0,0,0);
      ah = __builtin_amdgcn_mfma_f32_16x16x32_bf16(avl, uh[kk], ah, 0,0,0);
      ah = __builtin_amdgcn_mfma_f32_16x16x32_bf16(avh, uh[kk], ah, 0,0,0);
    }
    if (kq) {
      int slot = (kq-1)*2 + m;
      sRed[slot][0][lane] = az; sRed[slot][1][lane] = ar; sRed[slot][2][lane] = ah;
    }
    __syncthreads();
    if (kq == 0) {
      #pragma unroll
      for (int p = 0; p < 3; ++p) {
        int slot = p*2 + m;
        az += sRed[slot][0][lane]; ar += sRed[slot][1][lane]; ah += sRed[slot][2][lane];
      }
      #pragma unroll
      for (int r = 0; r < 4; ++r) {
        int s = s0 + m*16 + kg*4 + r;
        float z  = sigmoid_f(xzv[r] + az[r] + bz_);
        float rg = sigmoid_f(xrv[r] + ar[r] + br_);
        float hh = tanhf(xhv[r] + rg*(ah[r] + bh_));
        float hnew = z*hov[r] + (1.0f - z)*hh;
        hfn[(size_t)s*UNITS + u] = hnew;
        __bf16 hi = (__bf16)hnew;
        int ia = (((u >> 3) << 6) + s)*8 + (u & 7);
        hhin[ia] = hi;
        hlon[ia] = (__bf16)(hnew - (float)hi);
        if ((s >> 3) == mm)
          ret[(size_t)((((s & 7)*32 + t) << 3) + mm)*256 + (u & 255)] = hnew;
        if (t == 31 && s >= 56) st[(size_t)(s - 56)*UNITS + u] = hnew;
      }
    }
    grid_barrier(bar, bar + 32, nb);
  }
}

extern "C" void kernel_launch(void* const* d_in, const int* in_sizes, int n_in,
                              void* d_out, int out_size, void* d_ws, size_t ws_size,
                              hipStream_t stream) {
  const float* x  = (const float*)d_in[0];
  const float* h0 = (const float*)d_in[1];
  const float* W  = (const float*)d_in[2];
  const float* U  = (const float*)d_in[3];
  const float* b  = (const float*)d_in[4];
  float* ret = (float*)d_out;
  float* st  = ret + 524288;

  char* p = (char*)d_ws;
  __bf16* Ut = (__bf16*)p; p += 25165824;
  __bf16* Wt = (__bf16*)p; p += 25165824;
  __bf16* xb = (__bf16*)p; p += 1048576;
  float*  xp = (float*)p;  p += 50331648;
  float*  hf0  = (float*)p;  p += 524288;
  float*  hf1  = (float*)p;  p += 524288;
  __bf16* hhi0 = (__bf16*)p; p += 262144;
  __bf16* hhi1 = (__bf16*)p; p += 262144;
  __bf16* hlo0 = (__bf16*)p; p += 262144;
  __bf16* hlo1 = (__bf16*)p; p += 262144;
  unsigned* bar = (unsigned*)p; p += 256;   // bar[0]=counter, bar[32]=generation

  prep_misc<<<2048, 256, 0, stream>>>(x, h0, xb, hf0, hhi0, hlo0, bar);
  transpose_cast<<<dim3(96,32,2), 256, 0, stream>>>(W, U, Wt, Ut);
  xp_gemm<<<dim3(96,4), 512, 0, stream>>>(xb, Wt, b, xp);

  const float* brec = b + NC;
  void* args[] = { (void*)&Ut, (void*)&xp, (void*)&brec,
                   (void*)&hf0, (void*)&hf1, (void*)&hhi0, (void*)&hhi1,
                   (void*)&hlo0, (void*)&hlo1, (void*)&ret, (void*)&st, (void*)&bar };
  hipLaunchCooperativeKernel((const void*)gru_persist, dim3(256), dim3(512),
                             args, 0, stream);
}

// Round 4
// 748.827 us; speedup vs baseline: 2.4202x; 1.0866x over previous
//
#include <hip/hip_runtime.h>
#include <hip/hip_bf16.h>

typedef __bf16 bf16x8 __attribute__((ext_vector_type(8)));
typedef float f32x4 __attribute__((ext_vector_type(4)));

#define UNITS   2048
#define NC      6144
#define TSTEPS  32

__device__ __forceinline__ float sigmoid_f(float v){ return 1.0f/(1.0f+__expf(-v)); }

// ---- prep: cast x to bf16; init h hi/lo ([u>>3][s][u&7]); zero barrier state ----
__global__ __launch_bounds__(256) void prep_misc(
    const float* __restrict__ x, const float* __restrict__ h0,
    __bf16* __restrict__ xb,
    __bf16* __restrict__ hhi8, __bf16* __restrict__ hlo8,
    unsigned* __restrict__ bar)
{
  int i = blockIdx.x*256 + threadIdx.x;
  if (i < 640) bar[i] = 0;     // 20 cache lines of barrier state
  if (i < 524288) xb[i] = (__bf16)x[i];
  if (i < 131072) {
    int s = i >> 11, u = i & 2047;
    float v = h0[((s & 7) << 11) + u];
    __bf16 hi = (__bf16)v;
    int ia = (((u >> 3) << 6) + s) * 8 + (u & 7);
    hhi8[ia] = hi;
    hlo8[ia] = (__bf16)(v - (float)hi);
  }
}

// ---- transpose+cast: src (2048 x 6144 f32, KxN) -> dst (6144 x 2048 bf16, NxK) ----
__global__ __launch_bounds__(256) void transpose_cast(
    const float* __restrict__ W, const float* __restrict__ U,
    __bf16* __restrict__ Wt, __bf16* __restrict__ Ut)
{
  __shared__ float tile[64][65];
  const float* src = blockIdx.z ? U : W;
  __bf16* dst = blockIdx.z ? Ut : Wt;
  int n0 = blockIdx.x*64, k0 = blockIdx.y*64;
  int lane = threadIdx.x & 63, grp = threadIdx.x >> 6;
  #pragma unroll
  for (int r = grp; r < 64; r += 4)
    tile[r][lane] = src[(size_t)(k0+r)*NC + n0 + lane];
  __syncthreads();
  #pragma unroll
  for (int r = grp; r < 64; r += 4)
    dst[(size_t)(n0+r)*UNITS + k0 + lane] = (__bf16)tile[lane][r];
}

// ---- xp GEMM, LDS-staged B, register prefix over l ----
__global__ __launch_bounds__(512) void xp_gemm(
    const __bf16* __restrict__ xb, const __bf16* __restrict__ Wt,
    const float* __restrict__ bin, float* __restrict__ xp)
{
  __shared__ __align__(16) short sB[64*256];   // 32 KB, [col][k256] swizzled
  int n0 = blockIdx.x*64, bt0 = blockIdx.y*64;
  int tid = threadIdx.x;
  int lane = tid & 63, w = tid >> 6;
  int wm = w & 3, wn = w >> 2;
  int nl = lane & 15, kg = lane >> 4;
  f32x4 acc[2] = {{0,0,0,0},{0,0,0,0}};
  for (int l = 0; l < 8; ++l) {
    __syncthreads();
    #pragma unroll
    for (int i = 0; i < 4; ++i) {
      int e = tid + i*512;
      int col = e >> 5, ch = e & 31;
      bf16x8 v = *(const bf16x8*)(Wt + (size_t)(n0+col)*UNITS + l*256 + ch*8);
      int off = ((col<<9) | (ch<<4)) ^ ((col&7)<<4);
      *(bf16x8*)((char*)sB + off) = v;
    }
    __syncthreads();
    const __bf16* abase = xb + ((size_t)(bt0 + wm*16 + nl)*8 + l)*256 + kg*8;
    #pragma unroll
    for (int kk = 0; kk < 256; kk += 32) {
      bf16x8 a = *(const bf16x8*)(abase + kk);
      #pragma unroll
      for (int nt = 0; nt < 2; ++nt) {
        int col = wn*32 + nt*16 + nl;
        int off = ((col<<9) | ((kk + kg*8)<<1)) ^ ((col&7)<<4);
        bf16x8 bfr = *(const bf16x8*)((const char*)sB + off);
        acc[nt] = __builtin_amdgcn_mfma_f32_16x16x32_bf16(a, bfr, acc[nt], 0,0,0);
      }
    }
    int orow = bt0 + wm*16 + kg*4;
    #pragma unroll
    for (int nt = 0; nt < 2; ++nt) {
      int col = n0 + wn*32 + nt*16 + nl;
      float bv = bin[col];
      #pragma unroll
      for (int r = 0; r < 4; ++r) {
        int rr = orow + r;
        int b_ = rr >> 5, t_ = rr & 31;
        xp[(size_t)((l*8 + b_)*32 + t_)*NC + col] = acc[nt][r] + bv;
      }
    }
  }
}

// ---- two-level per-seq-half barrier: 8 groups x 16 blocks, monotonic targets ----
// bar layout (uint, one 128B line each): [half*8+g]*32 group cnt, [16+half]*32 root,
// [18+half]*32 generation
__device__ __forceinline__ void half_barrier(unsigned* bar, int half, int idxInHalf, int t)
{
  __syncthreads();
  if (threadIdx.x == 0) {
    __threadfence();   // release: publish this block's h stores
    unsigned* grp  = bar + (half*8 + (idxInHalf & 7))*32;
    unsigned* root = bar + (16 + half)*32;
    unsigned* gen  = bar + (18 + half)*32;
    unsigned tgt = (unsigned)(t + 1);
    unsigned a = __hip_atomic_fetch_add(grp, 1u, __ATOMIC_ACQ_REL, __HIP_MEMORY_SCOPE_AGENT) + 1u;
    if (a == tgt*16u) {
      unsigned r = __hip_atomic_fetch_add(root, 1u, __ATOMIC_ACQ_REL, __HIP_MEMORY_SCOPE_AGENT) + 1u;
      if (r == tgt*8u)
        __hip_atomic_store(gen, tgt, __ATOMIC_RELEASE, __HIP_MEMORY_SCOPE_AGENT);
    }
    while (__hip_atomic_load(gen, __ATOMIC_RELAXED, __HIP_MEMORY_SCOPE_AGENT) < tgt)
      __builtin_amdgcn_s_sleep(1);
    __threadfence();   // acquire: invalidate stale cached h
  }
  __syncthreads();
}

// ---- persistent GRU: all 32 steps, U resident in LDS(z,r)+VGPR(hh), h_prev in regs ----
__global__ __launch_bounds__(512, 2) void gru_persist(
    const __bf16* __restrict__ Ut, const float* __restrict__ xp, const float* __restrict__ brec,
    const float* __restrict__ h0,
    __bf16* __restrict__ hhi0, __bf16* __restrict__ hhi1,
    __bf16* __restrict__ hlo0, __bf16* __restrict__ hlo1,
    float* __restrict__ ret, float* __restrict__ st, unsigned* __restrict__ bar)
{
  __shared__ __align__(16) short sU[2*16*2048];    // 128 KB: gates z,r [g][col16][k2048] swizzled
  __shared__ __align__(16) f32x4 sRed[6][3][64];   // 18 KB reduction scratch

  int tid = threadIdx.x;
  int lane = tid & 63, w = tid >> 6;
  int m = w & 1, kq = w >> 1;
  int half = blockIdx.x & 1;
  int idxInHalf = blockIdx.x >> 1;
  int u0 = idxInHalf * 16;
  int s0 = half * 32;
  int nl = lane & 15, kg = lane >> 4;

  // stage U gates z,r into LDS (coalesced along k)
  #pragma unroll
  for (int i = 0; i < 16; ++i) {
    int e = tid + i*512;
    int g = e >> 12, col = (e >> 8) & 15, ch = e & 255;
    bf16x8 v = *(const bf16x8*)(Ut + (size_t)(g*UNITS + u0 + col)*UNITS + ch*8);
    int off = ((g<<16) | (col<<12) | (ch<<4)) ^ ((col&7)<<4);
    *(bf16x8*)((char*)sU + off) = v;
  }
  // gate hh fragments in VGPRs: wave (m,kq) holds K-slice kq*512..+512
  bf16x8 uh[16];
  #pragma unroll
  for (int kk = 0; kk < 16; ++kk)
    uh[kk] = *(const bf16x8*)(Ut + (size_t)(2*UNITS + u0 + nl)*UNITS + kq*512 + kk*32 + kg*8);
  __syncthreads();

  int u = u0 + nl;
  float bz_ = brec[u], br_ = brec[2048+u], bh_ = brec[4096+u];
  int mm = u0 >> 8;

  // h_prev for this thread's 4 (s,u) outputs lives in registers
  float hprev[4];
  #pragma unroll
  for (int r = 0; r < 4; ++r) {
    int s = s0 + m*16 + kg*4 + r;
    hprev[r] = h0[((s & 7) << 11) + u];
  }

  for (int t = 0; t < TSTEPS; ++t) {
    const __bf16* hhic = (t&1) ? hhi1 : hhi0;
    __bf16*       hhin = (t&1) ? hhi0 : hhi1;
    const __bf16* hloc = (t&1) ? hlo1 : hlo0;
    __bf16*       hlon = (t&1) ? hlo0 : hlo1;

    // hoist scattered xp loads: hide their latency under the MFMA loop
    float xzv[4], xrv[4], xhv[4];
    if (kq == 0) {
      #pragma unroll
      for (int r = 0; r < 4; ++r) {
        int s = s0 + m*16 + kg*4 + r;
        const float* xrow = xp + ((size_t)s*32 + t)*NC;
        xzv[r] = xrow[u];
        xrv[r] = xrow[2048+u];
        xhv[r] = xrow[4096+u];
      }
    }

    f32x4 az = {0,0,0,0}, ar = {0,0,0,0}, ah = {0,0,0,0};
    const __bf16* Ah = hhic + ((size_t)((kq*64 + kg)*64) + s0 + m*16 + nl)*8;
    const __bf16* Al = hloc + ((size_t)((kq*64 + kg)*64) + s0 + m*16 + nl)*8;
    #pragma unroll
    for (int kk = 0; kk < 16; ++kk) {
      bf16x8 avh = *(const bf16x8*)(Ah + (size_t)kk*2048);
      bf16x8 avl = *(const bf16x8*)(Al + (size_t)kk*2048);
      int kb = (kq*512 + kk*32 + kg*8) << 1;
      int offz = ((0<<16) | (nl<<12) | kb) ^ ((nl&7)<<4);
      int offr = ((1<<16) | (nl<<12) | kb) ^ ((nl&7)<<4);
      bf16x8 bz = *(const bf16x8*)((const char*)sU + offz);
      bf16x8 br = *(const bf16x8*)((const char*)sU + offr);
      az = __builtin_amdgcn_mfma_f32_16x16x32_bf16(avl, bz, az, 0,0,0);
      az = __builtin_amdgcn_mfma_f32_16x16x32_bf16(avh, bz, az, 0,0,0);
      ar = __builtin_amdgcn_mfma_f32_16x16x32_bf16(avl, br, ar, 0,0,0);
      ar = __builtin_amdgcn_mfma_f32_16x16x32_bf16(avh, br, ar, 0,0,0);
      ah = __builtin_amdgcn_mfma_f32_16x16x32_bf16(avl, uh[kk], ah, 0,0,0);
      ah = __builtin_amdgcn_mfma_f32_16x16x32_bf16(avh, uh[kk], ah, 0,0,0);
    }
    if (kq) {
      int slot = (kq-1)*2 + m;
      sRed[slot][0][lane] = az; sRed[slot][1][lane] = ar; sRed[slot][2][lane] = ah;
    }
    __syncthreads();
    if (kq == 0) {
      #pragma unroll
      for (int p = 0; p < 3; ++p) {
        int slot = p*2 + m;
        az += sRed[slot][0][lane]; ar += sRed[slot][1][lane]; ah += sRed[slot][2][lane];
      }
      #pragma unroll
      for (int r = 0; r < 4; ++r) {
        int s = s0 + m*16 + kg*4 + r;
        float z  = sigmoid_f(xzv[r] + az[r] + bz_);
        float rg = sigmoid_f(xrv[r] + ar[r] + br_);
        float hh = tanhf(xhv[r] + rg*(ah[r] + bh_));
        float hnew = z*hprev[r] + (1.0f - z)*hh;
        hprev[r] = hnew;
        __bf16 hi = (__bf16)hnew;
        int ia = (((u >> 3) << 6) + s)*8 + (u & 7);
        hhin[ia] = hi;
        hlon[ia] = (__bf16)(hnew - (float)hi);
        if ((s >> 3) == mm)
          ret[(size_t)((((s & 7)*32 + t) << 3) + mm)*256 + (u & 255)] = hnew;
        if (t == 31 && s >= 56) st[(size_t)(s - 56)*UNITS + u] = hnew;
      }
    }
    if (t < TSTEPS - 1)
      half_barrier(bar, half, idxInHalf, t);
  }
}

extern "C" void kernel_launch(void* const* d_in, const int* in_sizes, int n_in,
                              void* d_out, int out_size, void* d_ws, size_t ws_size,
                              hipStream_t stream) {
  const float* x  = (const float*)d_in[0];
  const float* h0 = (const float*)d_in[1];
  const float* W  = (const float*)d_in[2];
  const float* U  = (const float*)d_in[3];
  const float* b  = (const float*)d_in[4];
  float* ret = (float*)d_out;
  float* st  = ret + 524288;

  char* p = (char*)d_ws;
  __bf16* Ut = (__bf16*)p; p += 25165824;
  __bf16* Wt = (__bf16*)p; p += 25165824;
  __bf16* xb = (__bf16*)p; p += 1048576;
  float*  xp = (float*)p;  p += 50331648;
  __bf16* hhi0 = (__bf16*)p; p += 262144;
  __bf16* hhi1 = (__bf16*)p; p += 262144;
  __bf16* hlo0 = (__bf16*)p; p += 262144;
  __bf16* hlo1 = (__bf16*)p; p += 262144;
  unsigned* bar = (unsigned*)p; p += 2560;  // 20 x 128B lines

  prep_misc<<<2048, 256, 0, stream>>>(x, h0, xb, hhi0, hlo0, bar);
  transpose_cast<<<dim3(96,32,2), 256, 0, stream>>>(W, U, Wt, Ut);
  xp_gemm<<<dim3(96,4), 512, 0, stream>>>(xb, Wt, b, xp);

  const float* brec = b + NC;
  void* args[] = { (void*)&Ut, (void*)&xp, (void*)&brec, (void*)&h0,
                   (void*)&hhi0, (void*)&hhi1, (void*)&hlo0, (void*)&hlo1,
                   (void*)&ret, (void*)&st, (void*)&bar };
  hipLaunchCooperativeKernel((const void*)gru_persist, dim3(256), dim3(512),
                             args, 0, stream);
}

// Round 5
// 484.298 us; speedup vs baseline: 3.7421x; 1.5462x over previous
//
#include <hip/hip_runtime.h>
#include <hip/hip_bf16.h>

typedef __bf16 bf16x8 __attribute__((ext_vector_type(8)));
typedef float f32x4 __attribute__((ext_vector_type(4)));

#define UNITS   2048
#define NC      6144
#define TSTEPS  32

__device__ __forceinline__ float sigmoid_f(float v){ return 1.0f/(1.0f+__expf(-v)); }

// ---- prep: cast x to bf16; init h hi/lo (plain [s][u]); zero barrier state ----
__global__ __launch_bounds__(256) void prep_misc(
    const float* __restrict__ x, const float* __restrict__ h0,
    __bf16* __restrict__ xb,
    __bf16* __restrict__ hhi, __bf16* __restrict__ hlo,
    unsigned* __restrict__ bar)
{
  int i = blockIdx.x*256 + threadIdx.x;
  if (i < 640) bar[i] = 0;
  if (i < 524288) xb[i] = (__bf16)x[i];
  if (i < 131072) {
    int s = i >> 11, u = i & 2047;
    float v = h0[((s & 7) << 11) + u];
    __bf16 hi = (__bf16)v;
    hhi[i] = hi;
    hlo[i] = (__bf16)(v - (float)hi);
  }
}

// ---- transpose+cast: src (2048 x 6144 f32, KxN) -> dst (6144 x 2048 bf16, NxK) ----
__global__ __launch_bounds__(256) void transpose_cast(
    const float* __restrict__ W, const float* __restrict__ U,
    __bf16* __restrict__ Wt, __bf16* __restrict__ Ut)
{
  __shared__ float tile[64][65];
  const float* src = blockIdx.z ? U : W;
  __bf16* dst = blockIdx.z ? Ut : Wt;
  int n0 = blockIdx.x*64, k0 = blockIdx.y*64;
  int lane = threadIdx.x & 63, grp = threadIdx.x >> 6;
  #pragma unroll
  for (int r = grp; r < 64; r += 4)
    tile[r][lane] = src[(size_t)(k0+r)*NC + n0 + lane];
  __syncthreads();
  #pragma unroll
  for (int r = grp; r < 64; r += 4)
    dst[(size_t)(n0+r)*UNITS + k0 + lane] = (__bf16)tile[lane][r];
}

// ---- xp GEMM, LDS-staged B, register prefix over l ----
__global__ __launch_bounds__(512) void xp_gemm(
    const __bf16* __restrict__ xb, const __bf16* __restrict__ Wt,
    const float* __restrict__ bin, float* __restrict__ xp)
{
  __shared__ __align__(16) short sB[64*256];
  int n0 = blockIdx.x*64, bt0 = blockIdx.y*64;
  int tid = threadIdx.x;
  int lane = tid & 63, w = tid >> 6;
  int wm = w & 3, wn = w >> 2;
  int nl = lane & 15, kg = lane >> 4;
  f32x4 acc[2] = {{0,0,0,0},{0,0,0,0}};
  for (int l = 0; l < 8; ++l) {
    __syncthreads();
    #pragma unroll
    for (int i = 0; i < 4; ++i) {
      int e = tid + i*512;
      int col = e >> 5, ch = e & 31;
      bf16x8 v = *(const bf16x8*)(Wt + (size_t)(n0+col)*UNITS + l*256 + ch*8);
      int off = ((col<<9) | (ch<<4)) ^ ((col&7)<<4);
      *(bf16x8*)((char*)sB + off) = v;
    }
    __syncthreads();
    const __bf16* abase = xb + ((size_t)(bt0 + wm*16 + nl)*8 + l)*256 + kg*8;
    #pragma unroll
    for (int kk = 0; kk < 256; kk += 32) {
      bf16x8 a = *(const bf16x8*)(abase + kk);
      #pragma unroll
      for (int nt = 0; nt < 2; ++nt) {
        int col = wn*32 + nt*16 + nl;
        int off = ((col<<9) | ((kk + kg*8)<<1)) ^ ((col&7)<<4);
        bf16x8 bfr = *(const bf16x8*)((const char*)sB + off);
        acc[nt] = __builtin_amdgcn_mfma_f32_16x16x32_bf16(a, bfr, acc[nt], 0,0,0);
      }
    }
    int orow = bt0 + wm*16 + kg*4;
    #pragma unroll
    for (int nt = 0; nt < 2; ++nt) {
      int col = n0 + wn*32 + nt*16 + nl;
      float bv = bin[col];
      #pragma unroll
      for (int r = 0; r < 4; ++r) {
        int rr = orow + r;
        int b_ = rr >> 5, t_ = rr & 31;
        xp[(size_t)((l*8 + b_)*32 + t_)*NC + col] = acc[nt][r] + bv;
      }
    }
  }
}

// ---- fence-free half barrier: h is coherent via sc1 write-through stores;
//      acquire side is invalidate-only (no L2 writeback) ----
__device__ __forceinline__ void half_barrier(unsigned* bar, int half, int idxInHalf, int t)
{
  __syncthreads();   // compiler drains vmcnt(0) here -> sc1 h stores are at MALL
  if (threadIdx.x == 0) {
    unsigned* grp  = bar + (half*8 + (idxInHalf & 7))*32;
    unsigned* root = bar + (16 + half)*32;
    unsigned* gen  = bar + (18 + half)*32;
    unsigned tgt = (unsigned)(t + 1);
    unsigned a = __hip_atomic_fetch_add(grp, 1u, __ATOMIC_RELAXED, __HIP_MEMORY_SCOPE_AGENT) + 1u;
    if (a == tgt*16u) {
      unsigned r = __hip_atomic_fetch_add(root, 1u, __ATOMIC_RELAXED, __HIP_MEMORY_SCOPE_AGENT) + 1u;
      if (r == tgt*8u)
        __hip_atomic_store(gen, tgt, __ATOMIC_RELEASE, __HIP_MEMORY_SCOPE_AGENT);
    }
    while (__hip_atomic_load(gen, __ATOMIC_RELAXED, __HIP_MEMORY_SCOPE_AGENT) < tgt)
      __builtin_amdgcn_s_sleep(1);
    __builtin_amdgcn_fence(__ATOMIC_ACQUIRE, "agent");  // waitcnt + buffer_inv sc1 only
  }
  __syncthreads();
}

// ---- persistent GRU: U resident in LDS(z,r)+VGPR(hh); h [s][u] via MALL ----
__global__ __launch_bounds__(512, 2) void gru_persist(
    const __bf16* __restrict__ Ut, const float* __restrict__ xp, const float* __restrict__ brec,
    const float* __restrict__ h0,
    __bf16* __restrict__ hhi0, __bf16* __restrict__ hhi1,
    __bf16* __restrict__ hlo0, __bf16* __restrict__ hlo1,
    float* __restrict__ ret, float* __restrict__ st, unsigned* __restrict__ bar)
{
  __shared__ __align__(16) short sU[2*16*2048];    // 128 KB z,r gates
  __shared__ __align__(16) f32x4 sRed[6][3][64];   // 18 KB kq partials
  __shared__ __align__(16) f32x4 sGate[2][3][64];  // 6 KB transpose exchange

  int tid = threadIdx.x;
  int lane = tid & 63, w = tid >> 6;
  int m = w & 1, kq = w >> 1;
  int half = blockIdx.x & 1;
  int idxInHalf = blockIdx.x >> 1;
  int u0 = idxInHalf * 16;
  int s0 = half * 32;
  int nl = lane & 15, kg = lane >> 4;

  // stage U gates z,r into LDS
  #pragma unroll
  for (int i = 0; i < 16; ++i) {
    int e = tid + i*512;
    int g = e >> 12, col = (e >> 8) & 15, ch = e & 255;
    bf16x8 v = *(const bf16x8*)(Ut + (size_t)(g*UNITS + u0 + col)*UNITS + ch*8);
    int off = ((g<<16) | (col<<12) | (ch<<4)) ^ ((col&7)<<4);
    *(bf16x8*)((char*)sU + off) = v;
  }
  // hh-gate fragments in VGPRs
  bf16x8 uh[16];
  #pragma unroll
  for (int kk = 0; kk < 16; ++kk)
    uh[kk] = *(const bf16x8*)(Ut + (size_t)(2*UNITS + u0 + nl)*UNITS + kq*512 + kk*32 + kg*8);
  __syncthreads();

  // transposed epilogue ownership (threads 0..127): (s = s0 + tid>>2, u4 = u0 + (tid&3)*4)
  int s_ = tid >> 2, uoff = (tid & 3) * 4;
  int sg = s0 + s_;
  int u4 = u0 + uoff;
  int mp = s_ >> 4, rr_ = s_ & 15, kgp = rr_ >> 2, rp = rr_ & 3;
  int mm = u0 >> 8;

  f32x4 bz4, br4, bh4, hprev;
  if (tid < 128) {
    bz4 = *(const f32x4*)(brec + u4);
    br4 = *(const f32x4*)(brec + 2048 + u4);
    bh4 = *(const f32x4*)(brec + 4096 + u4);
    hprev = *(const f32x4*)(h0 + ((sg & 7) << 11) + u4);
  }

  for (int t = 0; t < TSTEPS; ++t) {
    const __bf16* hhic = (t&1) ? hhi1 : hhi0;
    __bf16*       hhin = (t&1) ? hhi0 : hhi1;
    const __bf16* hloc = (t&1) ? hlo1 : hlo0;
    __bf16*       hlon = (t&1) ? hlo0 : hlo1;

    f32x4 az = {0,0,0,0}, ar = {0,0,0,0}, ah = {0,0,0,0};
    const __bf16* Ah = hhic + (size_t)(s0 + m*16 + nl)*UNITS + kq*512 + kg*8;
    const __bf16* Al = hloc + (size_t)(s0 + m*16 + nl)*UNITS + kq*512 + kg*8;
    #pragma unroll
    for (int kk = 0; kk < 16; ++kk) {
      bf16x8 avh = *(const bf16x8*)(Ah + kk*32);
      bf16x8 avl = *(const bf16x8*)(Al + kk*32);
      int kb = (kq*512 + kk*32 + kg*8) << 1;
      int offz = ((0<<16) | (nl<<12) | kb) ^ ((nl&7)<<4);
      int offr = ((1<<16) | (nl<<12) | kb) ^ ((nl&7)<<4);
      bf16x8 bz = *(const bf16x8*)((const char*)sU + offz);
      bf16x8 br = *(const bf16x8*)((const char*)sU + offr);
      az = __builtin_amdgcn_mfma_f32_16x16x32_bf16(avl, bz, az, 0,0,0);
      az = __builtin_amdgcn_mfma_f32_16x16x32_bf16(avh, bz, az, 0,0,0);
      ar = __builtin_amdgcn_mfma_f32_16x16x32_bf16(avl, br, ar, 0,0,0);
      ar = __builtin_amdgcn_mfma_f32_16x16x32_bf16(avh, br, ar, 0,0,0);
      ah = __builtin_amdgcn_mfma_f32_16x16x32_bf16(avl, uh[kk], ah, 0,0,0);
      ah = __builtin_amdgcn_mfma_f32_16x16x32_bf16(avh, uh[kk], ah, 0,0,0);
    }

    // prefetch xp (transposed ownership) while reduction happens
    f32x4 xz4, xr4, xh4;
    if (tid < 128) {
      const float* xrow = xp + ((size_t)sg*32 + t)*NC;
      xz4 = *(const f32x4*)(xrow + u4);
      xr4 = *(const f32x4*)(xrow + 2048 + u4);
      xh4 = *(const f32x4*)(xrow + 4096 + u4);
    }

    if (kq) {
      int slot = (kq-1)*2 + m;
      sRed[slot][0][lane] = az; sRed[slot][1][lane] = ar; sRed[slot][2][lane] = ah;
    }
    __syncthreads();
    if (kq == 0) {
      #pragma unroll
      for (int p = 0; p < 3; ++p) {
        int slot = p*2 + m;
        az += sRed[slot][0][lane]; ar += sRed[slot][1][lane]; ah += sRed[slot][2][lane];
      }
      sGate[m][0][lane] = az; sGate[m][1][lane] = ar; sGate[m][2][lane] = ah;
    }
    __syncthreads();

    if (tid < 128) {
      const float* gbase = (const float*)sGate;
      float hv[4];
      unsigned long long hiW = 0, loW = 0;
      #pragma unroll
      for (int j = 0; j < 4; ++j) {
        int lanep = kgp*16 + uoff + j;
        int fi = ((mp*3 + 0)*64 + lanep)*4 + rp;
        float vz = gbase[fi];
        float vr = gbase[fi + 256];
        float vh = gbase[fi + 512];
        float z  = sigmoid_f(xz4[j] + vz + bz4[j]);
        float rg = sigmoid_f(xr4[j] + vr + br4[j]);
        float hh = tanhf(xh4[j] + rg*(vh + bh4[j]));
        float hn = z*hprev[j] + (1.0f - z)*hh;
        hprev[j] = hn;
        hv[j] = hn;
        __bf16 hb = (__bf16)hn;
        float hif = (float)hb;
        __bf16 lb = (__bf16)(hn - hif);
        hiW |= (unsigned long long)__builtin_bit_cast(unsigned short, hb) << (16*j);
        loW |= (unsigned long long)__builtin_bit_cast(unsigned short, lb) << (16*j);
      }
      // coherent write-through stores (sc1): land at MALL, no dirty L2
      __hip_atomic_store((unsigned long long*)(hhin + (size_t)sg*UNITS + u4), hiW,
                         __ATOMIC_RELAXED, __HIP_MEMORY_SCOPE_AGENT);
      __hip_atomic_store((unsigned long long*)(hlon + (size_t)sg*UNITS + u4), loW,
                         __ATOMIC_RELAXED, __HIP_MEMORY_SCOPE_AGENT);
      if ((sg >> 3) == mm) {
        f32x4 o = {hv[0], hv[1], hv[2], hv[3]};
        *(f32x4*)(ret + (size_t)((((sg & 7)*32 + t) << 3) + mm)*256 + (u4 & 255)) = o;
      }
      if (t == 31 && sg >= 56) {
        f32x4 o = {hv[0], hv[1], hv[2], hv[3]};
        *(f32x4*)(st + (size_t)(sg - 56)*UNITS + u4) = o;
      }
    }
    if (t < TSTEPS - 1)
      half_barrier(bar, half, idxInHalf, t);
  }
}

extern "C" void kernel_launch(void* const* d_in, const int* in_sizes, int n_in,
                              void* d_out, int out_size, void* d_ws, size_t ws_size,
                              hipStream_t stream) {
  const float* x  = (const float*)d_in[0];
  const float* h0 = (const float*)d_in[1];
  const float* W  = (const float*)d_in[2];
  const float* U  = (const float*)d_in[3];
  const float* b  = (const float*)d_in[4];
  float* ret = (float*)d_out;
  float* st  = ret + 524288;

  char* p = (char*)d_ws;
  __bf16* Ut = (__bf16*)p; p += 25165824;
  __bf16* Wt = (__bf16*)p; p += 25165824;
  __bf16* xb = (__bf16*)p; p += 1048576;
  float*  xp = (float*)p;  p += 50331648;
  __bf16* hhi0 = (__bf16*)p; p += 262144;
  __bf16* hhi1 = (__bf16*)p; p += 262144;
  __bf16* hlo0 = (__bf16*)p; p += 262144;
  __bf16* hlo1 = (__bf16*)p; p += 262144;
  unsigned* bar = (unsigned*)p; p += 2560;

  prep_misc<<<2048, 256, 0, stream>>>(x, h0, xb, hhi0, hlo0, bar);
  transpose_cast<<<dim3(96,32,2), 256, 0, stream>>>(W, U, Wt, Ut);
  xp_gemm<<<dim3(96,4), 512, 0, stream>>>(xb, Wt, b, xp);

  const float* brec = b + NC;
  void* args[] = { (void*)&Ut, (void*)&xp, (void*)&brec, (void*)&h0,
                   (void*)&hhi0, (void*)&hhi1, (void*)&hlo0, (void*)&hlo1,
                   (void*)&ret, (void*)&st, (void*)&bar };
  hipLaunchCooperativeKernel((const void*)gru_persist, dim3(256), dim3(512),
                             args, 0, stream);
}

// Round 6
// 427.894 us; speedup vs baseline: 4.2354x; 1.1318x over previous
//
#include <hip/hip_runtime.h>
#include <hip/hip_bf16.h>

typedef _Float16 f16x8 __attribute__((ext_vector_type(8)));
typedef float f32x4 __attribute__((ext_vector_type(4)));
typedef unsigned long long ull;

#define UNITS   2048
#define NC      6144
#define TSTEPS  32

__device__ __forceinline__ float sigmoid_f(float v){ return 1.0f/(1.0f+__expf(-v)); }

// ---- prep: cast x to fp16; init h (fp16 [s][u]); zero barrier state ----
__global__ __launch_bounds__(256) void prep_misc(
    const float* __restrict__ x, const float* __restrict__ h0,
    _Float16* __restrict__ xh, _Float16* __restrict__ hA,
    unsigned* __restrict__ bar)
{
  int i = blockIdx.x*256 + threadIdx.x;
  if (i < 640) bar[i] = 0;
  if (i < 524288) xh[i] = (_Float16)x[i];
  if (i < 131072) {
    int s = i >> 11, u = i & 2047;
    hA[i] = (_Float16)h0[((s & 7) << 11) + u];
  }
}

// ---- transpose+cast: src (2048 x 6144 f32, KxN) -> dst (6144 x 2048 fp16, NxK) ----
__global__ __launch_bounds__(256) void transpose_cast(
    const float* __restrict__ W, const float* __restrict__ U,
    _Float16* __restrict__ Wt, _Float16* __restrict__ Ut)
{
  __shared__ float tile[64][65];
  const float* src = blockIdx.z ? U : W;
  _Float16* dst = blockIdx.z ? Ut : Wt;
  int n0 = blockIdx.x*64, k0 = blockIdx.y*64;
  int lane = threadIdx.x & 63, grp = threadIdx.x >> 6;
  #pragma unroll
  for (int r = grp; r < 64; r += 4)
    tile[r][lane] = src[(size_t)(k0+r)*NC + n0 + lane];
  __syncthreads();
  #pragma unroll
  for (int r = grp; r < 64; r += 4)
    dst[(size_t)(n0+r)*UNITS + k0 + lane] = (_Float16)tile[lane][r];
}

// ---- xp GEMM: grid (96 n, 2 bt-halves of 128 rows), 512 threads ----
// waves: wm=w&3 (32 rows: 2 subtiles of 16), wn=w>>2 (32 cols: 2 tiles of 16)
__global__ __launch_bounds__(512) void xp_gemm(
    const _Float16* __restrict__ xh, const _Float16* __restrict__ Wt,
    const float* __restrict__ bin, float* __restrict__ xp)
{
  __shared__ __align__(16) short sB[64*256];   // 32 KB
  int n0 = blockIdx.x*64, bt0 = blockIdx.y*128;
  int tid = threadIdx.x;
  int lane = tid & 63, w = tid >> 6;
  int wm = w & 3, wn = w >> 2;
  int nl = lane & 15, kg = lane >> 4;
  f32x4 acc[2][2] = {{{0,0,0,0},{0,0,0,0}},{{0,0,0,0},{0,0,0,0}}};
  for (int l = 0; l < 8; ++l) {
    __syncthreads();
    #pragma unroll
    for (int i = 0; i < 4; ++i) {
      int e = tid + i*512;
      int col = e >> 5, ch = e & 31;
      f16x8 v = *(const f16x8*)(Wt + (size_t)(n0+col)*UNITS + l*256 + ch*8);
      int off = ((col<<9) | (ch<<4)) ^ ((col&7)<<4);
      *(f16x8*)((char*)sB + off) = v;
    }
    __syncthreads();
    #pragma unroll
    for (int kk = 0; kk < 256; kk += 32) {
      f16x8 a[2];
      #pragma unroll
      for (int sub = 0; sub < 2; ++sub) {
        int row = bt0 + wm*32 + sub*16 + nl;
        a[sub] = *(const f16x8*)(xh + ((size_t)row*8 + l)*256 + kg*8 + kk);
      }
      #pragma unroll
      for (int nt = 0; nt < 2; ++nt) {
        int col = wn*32 + nt*16 + nl;
        int off = ((col<<9) | ((kk + kg*8)<<1)) ^ ((col&7)<<4);
        f16x8 bfr = *(const f16x8*)((const char*)sB + off);
        #pragma unroll
        for (int sub = 0; sub < 2; ++sub)
          acc[sub][nt] = __builtin_amdgcn_mfma_f32_16x16x32_f16(a[sub], bfr, acc[sub][nt], 0,0,0);
      }
    }
    #pragma unroll
    for (int sub = 0; sub < 2; ++sub) {
      int orow = bt0 + wm*32 + sub*16 + kg*4;
      #pragma unroll
      for (int nt = 0; nt < 2; ++nt) {
        int col = n0 + wn*32 + nt*16 + nl;
        float bv = bin[col];
        #pragma unroll
        for (int r = 0; r < 4; ++r) {
          int rr = orow + r;
          int b_ = rr >> 5, t_ = rr & 31;
          xp[(size_t)((l*8 + b_)*32 + t_)*NC + col] = acc[sub][nt][r] + bv;
        }
      }
    }
  }
}

// ---- barrier: NO cache invalidate anywhere (h reads are sc1-coherent) ----
__device__ __forceinline__ void half_barrier(unsigned* bar, int half, int idxInHalf, int t)
{
  __syncthreads();   // compiler drains vmcnt(0) -> sc1 h stores at MALL
  if (threadIdx.x == 0) {
    unsigned* grp  = bar + (half*8 + (idxInHalf & 7))*32;
    unsigned* root = bar + (16 + half)*32;
    unsigned* gen  = bar + (18 + half)*32;
    unsigned tgt = (unsigned)(t + 1);
    unsigned a = __hip_atomic_fetch_add(grp, 1u, __ATOMIC_RELAXED, __HIP_MEMORY_SCOPE_AGENT) + 1u;
    if (a == tgt*16u) {
      unsigned r = __hip_atomic_fetch_add(root, 1u, __ATOMIC_RELAXED, __HIP_MEMORY_SCOPE_AGENT) + 1u;
      if (r == tgt*8u)
        __hip_atomic_store(gen, tgt, __ATOMIC_RELEASE, __HIP_MEMORY_SCOPE_AGENT);
    }
    while (__hip_atomic_load(gen, __ATOMIC_RELAXED, __HIP_MEMORY_SCOPE_AGENT) < tgt)
      __builtin_amdgcn_s_sleep(1);
  }
  __syncthreads();
  __builtin_amdgcn_fence(__ATOMIC_ACQUIRE, "workgroup");  // order loads; no L2 inv
}

// ---- persistent GRU: fp16 h, coherent sc1 loads/stores, U resident ----
__global__ __launch_bounds__(512, 2) void gru_persist(
    const _Float16* __restrict__ Ut, const float* __restrict__ xp, const float* __restrict__ brec,
    const float* __restrict__ h0,
    _Float16* __restrict__ hA, _Float16* __restrict__ hB,
    float* __restrict__ ret, float* __restrict__ st, unsigned* __restrict__ bar)
{
  __shared__ __align__(16) short sU[2*16*2048];    // 128 KB z,r gates
  __shared__ __align__(16) f32x4 sRed[6][3][64];   // 18 KB kq partials
  __shared__ __align__(16) f32x4 sGate[2][3][64];  // 6 KB transpose exchange

  int tid = threadIdx.x;
  int lane = tid & 63, w = tid >> 6;
  int m = w & 1, kq = w >> 1;
  int half = blockIdx.x & 1;
  int idxInHalf = blockIdx.x >> 1;
  int u0 = idxInHalf * 16;
  int s0 = half * 32;
  int nl = lane & 15, kg = lane >> 4;

  // stage U gates z,r into LDS
  #pragma unroll
  for (int i = 0; i < 16; ++i) {
    int e = tid + i*512;
    int g = e >> 12, col = (e >> 8) & 15, ch = e & 255;
    f16x8 v = *(const f16x8*)(Ut + (size_t)(g*UNITS + u0 + col)*UNITS + ch*8);
    int off = ((g<<16) | (col<<12) | (ch<<4)) ^ ((col&7)<<4);
    *(f16x8*)((char*)sU + off) = v;
  }
  // hh-gate fragments in VGPRs
  f16x8 uh[16];
  #pragma unroll
  for (int kk = 0; kk < 16; ++kk)
    uh[kk] = *(const f16x8*)(Ut + (size_t)(2*UNITS + u0 + nl)*UNITS + kq*512 + kk*32 + kg*8);
  __syncthreads();

  // transposed epilogue ownership (threads 0..127)
  int s_ = tid >> 2, uoff = (tid & 3) * 4;
  int sg = s0 + s_;
  int u4 = u0 + uoff;
  int mp = s_ >> 4, rr_ = s_ & 15, kgp = rr_ >> 2, rp = rr_ & 3;
  int mm = u0 >> 8;

  f32x4 bz4, br4, bh4, hprev;
  if (tid < 128) {
    bz4 = *(const f32x4*)(brec + u4);
    br4 = *(const f32x4*)(brec + 2048 + u4);
    bh4 = *(const f32x4*)(brec + 4096 + u4);
    hprev = *(const f32x4*)(h0 + ((sg & 7) << 11) + u4);
  }

  for (int t = 0; t < TSTEPS; ++t) {
    const _Float16* hc = (t&1) ? hB : hA;
    _Float16*       hn = (t&1) ? hA : hB;

    f32x4 az = {0,0,0,0}, ar = {0,0,0,0}, ah = {0,0,0,0};
    const _Float16* Ab = hc + (size_t)(s0 + m*16 + nl)*UNITS + kq*512 + kg*8;
    #pragma unroll
    for (int kk = 0; kk < 16; ++kk) {
      const ull* ap = (const ull*)(Ab + kk*32);
      ull l0 = __hip_atomic_load(ap,     __ATOMIC_RELAXED, __HIP_MEMORY_SCOPE_AGENT);
      ull l1 = __hip_atomic_load(ap + 1, __ATOMIC_RELAXED, __HIP_MEMORY_SCOPE_AGENT);
      f16x8 av;
      { ull tmp[2] = {l0, l1}; __builtin_memcpy(&av, tmp, 16); }
      int kb = (kq*512 + kk*32 + kg*8) << 1;
      int offz = ((0<<16) | (nl<<12) | kb) ^ ((nl&7)<<4);
      int offr = ((1<<16) | (nl<<12) | kb) ^ ((nl&7)<<4);
      f16x8 bz = *(const f16x8*)((const char*)sU + offz);
      f16x8 br = *(const f16x8*)((const char*)sU + offr);
      az = __builtin_amdgcn_mfma_f32_16x16x32_f16(av, bz, az, 0,0,0);
      ar = __builtin_amdgcn_mfma_f32_16x16x32_f16(av, br, ar, 0,0,0);
      ah = __builtin_amdgcn_mfma_f32_16x16x32_f16(av, uh[kk], ah, 0,0,0);
    }

    // prefetch xp while reduction happens
    f32x4 xz4, xr4, xh4;
    if (tid < 128) {
      const float* xrow = xp + ((size_t)sg*32 + t)*NC;
      xz4 = *(const f32x4*)(xrow + u4);
      xr4 = *(const f32x4*)(xrow + 2048 + u4);
      xh4 = *(const f32x4*)(xrow + 4096 + u4);
    }

    if (kq) {
      int slot = (kq-1)*2 + m;
      sRed[slot][0][lane] = az; sRed[slot][1][lane] = ar; sRed[slot][2][lane] = ah;
    }
    __syncthreads();
    if (kq == 0) {
      #pragma unroll
      for (int p = 0; p < 3; ++p) {
        int slot = p*2 + m;
        az += sRed[slot][0][lane]; ar += sRed[slot][1][lane]; ah += sRed[slot][2][lane];
      }
      sGate[m][0][lane] = az; sGate[m][1][lane] = ar; sGate[m][2][lane] = ah;
    }
    __syncthreads();

    if (tid < 128) {
      const float* gbase = (const float*)sGate;
      float hv[4];
      ull hw = 0;
      #pragma unroll
      for (int j = 0; j < 4; ++j) {
        int lanep = kgp*16 + uoff + j;
        int fi = ((mp*3 + 0)*64 + lanep)*4 + rp;
        float vz = gbase[fi];
        float vr = gbase[fi + 256];
        float vh = gbase[fi + 512];
        float z  = sigmoid_f(xz4[j] + vz + bz4[j]);
        float rg = sigmoid_f(xr4[j] + vr + br4[j]);
        float hh = tanhf(xh4[j] + rg*(vh + bh4[j]));
        float hnv = z*hprev[j] + (1.0f - z)*hh;
        hprev[j] = hnv;
        hv[j] = hnv;
        _Float16 hb = (_Float16)hnv;
        hw |= (ull)__builtin_bit_cast(unsigned short, hb) << (16*j);
      }
      // coherent write-through store (sc1): lands at MALL
      __hip_atomic_store((ull*)(hn + (size_t)sg*UNITS + u4), hw,
                         __ATOMIC_RELAXED, __HIP_MEMORY_SCOPE_AGENT);
      if ((sg >> 3) == mm) {
        f32x4 o = {hv[0], hv[1], hv[2], hv[3]};
        *(f32x4*)(ret + (size_t)((((sg & 7)*32 + t) << 3) + mm)*256 + (u4 & 255)) = o;
      }
      if (t == 31 && sg >= 56) {
        f32x4 o = {hv[0], hv[1], hv[2], hv[3]};
        *(f32x4*)(st + (size_t)(sg - 56)*UNITS + u4) = o;
      }
    }
    if (t < TSTEPS - 1)
      half_barrier(bar, half, idxInHalf, t);
  }
}

extern "C" void kernel_launch(void* const* d_in, const int* in_sizes, int n_in,
                              void* d_out, int out_size, void* d_ws, size_t ws_size,
                              hipStream_t stream) {
  const float* x  = (const float*)d_in[0];
  const float* h0 = (const float*)d_in[1];
  const float* W  = (const float*)d_in[2];
  const float* U  = (const float*)d_in[3];
  const float* b  = (const float*)d_in[4];
  float* ret = (float*)d_out;
  float* st  = ret + 524288;

  char* p = (char*)d_ws;
  _Float16* Ut = (_Float16*)p; p += 25165824;
  _Float16* Wt = (_Float16*)p; p += 25165824;
  _Float16* xh = (_Float16*)p; p += 1048576;
  float*    xp = (float*)p;    p += 50331648;
  _Float16* hA = (_Float16*)p; p += 262144;
  _Float16* hB = (_Float16*)p; p += 262144;
  unsigned* bar = (unsigned*)p; p += 2560;

  prep_misc<<<2048, 256, 0, stream>>>(x, h0, xh, hA, bar);
  transpose_cast<<<dim3(96,32,2), 256, 0, stream>>>(W, U, Wt, Ut);
  xp_gemm<<<dim3(96,2), 512, 0, stream>>>(xh, Wt, b, xp);

  const float* brec = b + NC;
  void* args[] = { (void*)&Ut, (void*)&xp, (void*)&brec, (void*)&h0,
                   (void*)&hA, (void*)&hB, (void*)&ret, (void*)&st, (void*)&bar };
  hipLaunchCooperativeKernel((const void*)gru_persist, dim3(256), dim3(512),
                             args, 0, stream);
}

// Round 7
// 277.970 us; speedup vs baseline: 6.5198x; 1.5394x over previous
//
#include <hip/hip_runtime.h>
#include <hip/hip_bf16.h>

typedef _Float16 f16x8 __attribute__((ext_vector_type(8)));
typedef float f32x4 __attribute__((ext_vector_type(4)));
typedef unsigned long long ull;

#define UNITS   2048
#define NC      6144
#define TSTEPS  32
#define HSTRIDE 131072   // one h buffer: 64 seqs x 2048 units fp16 (blocked layout)

__device__ __forceinline__ float sigmoid_f(float v){ return 1.0f/(1.0f+__expf(-v)); }

// ---- prep: cast x to fp16; init ring[0] (blocked [u>>3][s][u&7]); zero barrier ----
__global__ __launch_bounds__(256) void prep_misc(
    const float* __restrict__ x, const float* __restrict__ h0,
    _Float16* __restrict__ xh, _Float16* __restrict__ hRing,
    unsigned* __restrict__ bar)
{
  int i = blockIdx.x*256 + threadIdx.x;
  if (i < 640) bar[i] = 0;
  if (i < 524288) xh[i] = (_Float16)x[i];
  if (i < 131072) {
    int s = i >> 11, u = i & 2047;
    float v = h0[((s & 7) << 11) + u];
    hRing[(((u >> 3) << 6) + s)*8 + (u & 7)] = (_Float16)v;
  }
}

// ---- transpose+cast: src (2048 x 6144 f32, KxN) -> dst (6144 x 2048 fp16, NxK) ----
__global__ __launch_bounds__(256) void transpose_cast(
    const float* __restrict__ W, const float* __restrict__ U,
    _Float16* __restrict__ Wt, _Float16* __restrict__ Ut)
{
  __shared__ float tile[64][65];
  const float* src = blockIdx.z ? U : W;
  _Float16* dst = blockIdx.z ? Ut : Wt;
  int n0 = blockIdx.x*64, k0 = blockIdx.y*64;
  int lane = threadIdx.x & 63, grp = threadIdx.x >> 6;
  #pragma unroll
  for (int r = grp; r < 64; r += 4)
    tile[r][lane] = src[(size_t)(k0+r)*NC + n0 + lane];
  __syncthreads();
  #pragma unroll
  for (int r = grp; r < 64; r += 4)
    dst[(size_t)(n0+r)*UNITS + k0 + lane] = (_Float16)tile[lane][r];
}

// ---- xp GEMM: grid (96 n, 2 bt-halves of 128 rows), 512 threads ----
__global__ __launch_bounds__(512) void xp_gemm(
    const _Float16* __restrict__ xh, const _Float16* __restrict__ Wt,
    const float* __restrict__ bin, float* __restrict__ xp)
{
  __shared__ __align__(16) short sB[64*256];   // 32 KB
  int n0 = blockIdx.x*64, bt0 = blockIdx.y*128;
  int tid = threadIdx.x;
  int lane = tid & 63, w = tid >> 6;
  int wm = w & 3, wn = w >> 2;
  int nl = lane & 15, kg = lane >> 4;
  f32x4 acc[2][2] = {{{0,0,0,0},{0,0,0,0}},{{0,0,0,0},{0,0,0,0}}};
  for (int l = 0; l < 8; ++l) {
    __syncthreads();
    #pragma unroll
    for (int i = 0; i < 4; ++i) {
      int e = tid + i*512;
      int col = e >> 5, ch = e & 31;
      f16x8 v = *(const f16x8*)(Wt + (size_t)(n0+col)*UNITS + l*256 + ch*8);
      int off = ((col<<9) | (ch<<4)) ^ ((col&7)<<4);
      *(f16x8*)((char*)sB + off) = v;
    }
    __syncthreads();
    #pragma unroll
    for (int kk = 0; kk < 256; kk += 32) {
      f16x8 a[2];
      #pragma unroll
      for (int sub = 0; sub < 2; ++sub) {
        int row = bt0 + wm*32 + sub*16 + nl;
        a[sub] = *(const f16x8*)(xh + ((size_t)row*8 + l)*256 + kg*8 + kk);
      }
      #pragma unroll
      for (int nt = 0; nt < 2; ++nt) {
        int col = wn*32 + nt*16 + nl;
        int off = ((col<<9) | ((kk + kg*8)<<1)) ^ ((col&7)<<4);
        f16x8 bfr = *(const f16x8*)((const char*)sB + off);
        #pragma unroll
        for (int sub = 0; sub < 2; ++sub)
          acc[sub][nt] = __builtin_amdgcn_mfma_f32_16x16x32_f16(a[sub], bfr, acc[sub][nt], 0,0,0);
      }
    }
    #pragma unroll
    for (int sub = 0; sub < 2; ++sub) {
      int orow = bt0 + wm*32 + sub*16 + kg*4;
      #pragma unroll
      for (int nt = 0; nt < 2; ++nt) {
        int col = n0 + wn*32 + nt*16 + nl;
        float bv = bin[col];
        #pragma unroll
        for (int r = 0; r < 4; ++r) {
          int rr = orow + r;
          int b_ = rr >> 5, t_ = rr & 31;
          xp[(size_t)((l*8 + b_)*32 + t_)*NC + col] = acc[sub][nt][r] + bv;
        }
      }
    }
  }
}

// ---- barrier: sc1 h stores drained by the pre-barrier vmcnt(0); no invalidates ----
__device__ __forceinline__ void half_barrier(unsigned* bar, int half, int idxInHalf, int t)
{
  __syncthreads();
  if (threadIdx.x == 0) {
    unsigned* grp  = bar + (half*8 + (idxInHalf & 7))*32;
    unsigned* root = bar + (16 + half)*32;
    unsigned* gen  = bar + (18 + half)*32;
    unsigned tgt = (unsigned)(t + 1);
    unsigned a = __hip_atomic_fetch_add(grp, 1u, __ATOMIC_RELAXED, __HIP_MEMORY_SCOPE_AGENT) + 1u;
    if (a == tgt*16u) {
      unsigned r = __hip_atomic_fetch_add(root, 1u, __ATOMIC_RELAXED, __HIP_MEMORY_SCOPE_AGENT) + 1u;
      if (r == tgt*8u)
        __hip_atomic_store(gen, tgt, __ATOMIC_RELEASE, __HIP_MEMORY_SCOPE_AGENT);
    }
    while (__hip_atomic_load(gen, __ATOMIC_RELAXED, __HIP_MEMORY_SCOPE_AGENT) < tgt)
      __builtin_amdgcn_s_sleep(1);
  }
  __syncthreads();
  __builtin_amdgcn_fence(__ATOMIC_ACQUIRE, "workgroup");
}

// ---- persistent GRU: ring of single-writer h buffers; plain cached b128 A-loads ----
__global__ __launch_bounds__(512, 1) void gru_persist(
    const _Float16* __restrict__ Ut, const float* __restrict__ xp, const float* __restrict__ brec,
    const float* __restrict__ h0, _Float16* __restrict__ hRing,
    float* __restrict__ ret, float* __restrict__ st, unsigned* __restrict__ bar)
{
  __shared__ __align__(16) short sU[2*16*2048];     // 128 KB z,r gates
  __shared__ __align__(16) float sRed[6*3*288];     // 20.25 KB padded kq partials
  __shared__ __align__(16) float sGate[2*3*288];    // 6.75 KB padded exchange

  int tid = threadIdx.x;
  int lane = tid & 63, w = tid >> 6;
  int m = w & 1, kq = w >> 1;
  int half = blockIdx.x & 1;
  int idxInHalf = blockIdx.x >> 1;
  int u0 = idxInHalf * 16;
  int s0 = half * 32;
  int nl = lane & 15, kg = lane >> 4;
  int redidx = lane*4 + (lane>>3)*4;   // padded: stride 16B +16B per 8 lanes

  // stage U gates z,r into LDS
  #pragma unroll
  for (int i = 0; i < 16; ++i) {
    int e = tid + i*512;
    int g = e >> 12, col = (e >> 8) & 15, ch = e & 255;
    f16x8 v = *(const f16x8*)(Ut + (size_t)(g*UNITS + u0 + col)*UNITS + ch*8);
    int off = ((g<<16) | (col<<12) | (ch<<4)) ^ ((col&7)<<4);
    *(f16x8*)((char*)sU + off) = v;
  }
  // hh-gate fragments in VGPRs
  f16x8 uh[16];
  #pragma unroll
  for (int kk = 0; kk < 16; ++kk)
    uh[kk] = *(const f16x8*)(Ut + (size_t)(2*UNITS + u0 + nl)*UNITS + kq*512 + kk*32 + kg*8);
  __syncthreads();

  // transposed epilogue ownership (threads 0..127)
  int s_ = tid >> 2, uoff = (tid & 3) * 4;
  int sg = s0 + s_;
  int u4 = u0 + uoff;
  int mp = s_ >> 4, rr_ = s_ & 15, kgp = rr_ >> 2, rp = rr_ & 3;
  int mm = u0 >> 8;

  f32x4 bz4, br4, bh4, hprev;
  if (tid < 128) {
    bz4 = *(const f32x4*)(brec + u4);
    br4 = *(const f32x4*)(brec + 2048 + u4);
    bh4 = *(const f32x4*)(brec + 4096 + u4);
    hprev = *(const f32x4*)(h0 + ((sg & 7) << 11) + u4);
  }

  for (int t = 0; t < TSTEPS; ++t) {
    const _Float16* hc = hRing + (size_t)t*HSTRIDE;
    _Float16*       hn = hRing + (size_t)(t+1)*HSTRIDE;

    f32x4 az = {0,0,0,0}, ar = {0,0,0,0}, ah = {0,0,0,0};
    // blocked layout: elem (s, k) at ((k>>3)*64 + s)*8 + (k&7); coalesced b128 loads
    const _Float16* Ab = hc + (size_t)(((kq*64 + kg)*64) + s0 + m*16 + nl)*8;
    #pragma unroll
    for (int kk = 0; kk < 16; ++kk) {
      f16x8 av = *(const f16x8*)(Ab + kk*2048);
      int kb = (kq*512 + kk*32 + kg*8) << 1;
      int offz = ((0<<16) | (nl<<12) | kb) ^ ((nl&7)<<4);
      int offr = ((1<<16) | (nl<<12) | kb) ^ ((nl&7)<<4);
      f16x8 bz = *(const f16x8*)((const char*)sU + offz);
      f16x8 br = *(const f16x8*)((const char*)sU + offr);
      az = __builtin_amdgcn_mfma_f32_16x16x32_f16(av, bz, az, 0,0,0);
      ar = __builtin_amdgcn_mfma_f32_16x16x32_f16(av, br, ar, 0,0,0);
      ah = __builtin_amdgcn_mfma_f32_16x16x32_f16(av, uh[kk], ah, 0,0,0);
    }

    // prefetch xp while reduction happens
    f32x4 xz4, xr4, xh4;
    if (tid < 128) {
      const float* xrow = xp + ((size_t)sg*32 + t)*NC;
      xz4 = *(const f32x4*)(xrow + u4);
      xr4 = *(const f32x4*)(xrow + 2048 + u4);
      xh4 = *(const f32x4*)(xrow + 4096 + u4);
    }

    if (kq) {
      float* rp_ = &sRed[((kq-1)*2 + m)*3*288 + redidx];
      *(f32x4*)(rp_)       = az;
      *(f32x4*)(rp_ + 288) = ar;
      *(f32x4*)(rp_ + 576) = ah;
    }
    __syncthreads();
    if (kq == 0) {
      #pragma unroll
      for (int p = 0; p < 3; ++p) {
        const float* rp_ = &sRed[(p*2 + m)*3*288 + redidx];
        az += *(const f32x4*)(rp_);
        ar += *(const f32x4*)(rp_ + 288);
        ah += *(const f32x4*)(rp_ + 576);
      }
      float* gp = &sGate[m*3*288 + redidx];
      *(f32x4*)(gp)       = az;
      *(f32x4*)(gp + 288) = ar;
      *(f32x4*)(gp + 576) = ah;
    }
    __syncthreads();

    if (tid < 128) {
      float hv[4];
      ull hw = 0;
      #pragma unroll
      for (int j = 0; j < 4; ++j) {
        int lanep = kgp*16 + uoff + j;
        int gi = mp*3*288 + lanep*4 + (lanep>>3)*4 + rp;
        float vz = sGate[gi];
        float vr = sGate[gi + 288];
        float vh = sGate[gi + 576];
        float z  = sigmoid_f(xz4[j] + vz + bz4[j]);
        float rg = sigmoid_f(xr4[j] + vr + br4[j]);
        float hh = tanhf(xh4[j] + rg*(vh + bh4[j]));
        float hnv = z*hprev[j] + (1.0f - z)*hh;
        hprev[j] = hnv;
        hv[j] = hnv;
        _Float16 hb = (_Float16)hnv;
        hw |= (ull)__builtin_bit_cast(unsigned short, hb) << (16*j);
      }
      // publish h(t+1): sc1 write-through to MALL (single writer per line-segment)
      __hip_atomic_store((ull*)(hn + (size_t)(((u4 >> 3) << 6) + sg)*8 + (u4 & 7)), hw,
                         __ATOMIC_RELAXED, __HIP_MEMORY_SCOPE_AGENT);
      if ((sg >> 3) == mm) {
        f32x4 o = {hv[0], hv[1], hv[2], hv[3]};
        *(f32x4*)(ret + (size_t)((((sg & 7)*32 + t) << 3) + mm)*256 + (u4 & 255)) = o;
      }
      if (t == 31 && sg >= 56) {
        f32x4 o = {hv[0], hv[1], hv[2], hv[3]};
        *(f32x4*)(st + (size_t)(sg - 56)*UNITS + u4) = o;
      }
    }
    if (t < TSTEPS - 1)
      half_barrier(bar, half, idxInHalf, t);
  }
}

extern "C" void kernel_launch(void* const* d_in, const int* in_sizes, int n_in,
                              void* d_out, int out_size, void* d_ws, size_t ws_size,
                              hipStream_t stream) {
  const float* x  = (const float*)d_in[0];
  const float* h0 = (const float*)d_in[1];
  const float* W  = (const float*)d_in[2];
  const float* U  = (const float*)d_in[3];
  const float* b  = (const float*)d_in[4];
  float* ret = (float*)d_out;
  float* st  = ret + 524288;

  char* p = (char*)d_ws;
  _Float16* Ut = (_Float16*)p; p += 25165824;
  _Float16* Wt = (_Float16*)p; p += 25165824;
  _Float16* xh = (_Float16*)p; p += 1048576;
  float*    xp = (float*)p;    p += 50331648;
  _Float16* hRing = (_Float16*)p; p += 33ull * HSTRIDE * 2;   // 8.25 MB
  unsigned* bar = (unsigned*)p; p += 2560;

  prep_misc<<<2048, 256, 0, stream>>>(x, h0, xh, hRing, bar);
  transpose_cast<<<dim3(96,32,2), 256, 0, stream>>>(W, U, Wt, Ut);
  xp_gemm<<<dim3(96,2), 512, 0, stream>>>(xh, Wt, b, xp);

  const float* brec = b + NC;
  void* args[] = { (void*)&Ut, (void*)&xp, (void*)&brec, (void*)&h0,
                   (void*)&hRing, (void*)&ret, (void*)&st, (void*)&bar };
  hipLaunchCooperativeKernel((const void*)gru_persist, dim3(256), dim3(512),
                             args, 0, stream);
}